// Round 8
// baseline (399.560 us; speedup 1.0000x reference)
//
#include <hip/hip_runtime.h>
#include <hip/hip_bf16.h>

#define DFEAT 4096
#define NT 64        // K-tiles of 64
#define NITER 32     // 2 K-tiles per iteration

typedef __attribute__((ext_vector_type(8))) short bf16x8;
typedef __attribute__((ext_vector_type(4))) float f32x4;
typedef __attribute__((ext_vector_type(4))) float float4v;

__device__ inline unsigned short f32_to_bf16_rne(float f) {
  union { float f; unsigned u; } v; v.f = f;
  unsigned u = v.u;
  unsigned r = u + 0x7fffu + ((u >> 16) & 1u);
  return (unsigned short)(r >> 16);
}

// Wt[n][k] = psi[k] * sum_r omega[r][n] * g[r][(n-k)&4095], bf16, row-major [4096][4096]
__global__ void build_wt_kernel(const float* __restrict__ psi,
                                const float* __restrict__ omega,
                                const float* __restrict__ g,
                                unsigned short* __restrict__ Wt) {
  int n = blockIdx.x;
  float o0 = omega[n];
  float o1 = omega[DFEAT + n];
  float o2 = omega[2 * DFEAT + n];
  const float* g0 = g;
  const float* g1 = g + DFEAT;
  const float* g2 = g + 2 * DFEAT;
  for (int k = threadIdx.x; k < DFEAT; k += blockDim.x) {
    int idx = (n - k) & (DFEAT - 1);
    float w = o0 * g0[idx] + o1 * g1[idx] + o2 * g2[idx];
    w *= psi[k];
    Wt[(size_t)n * DFEAT + k] = f32_to_bf16_rne(w);
  }
}

// x (f32) -> bf16 bits, 8 elements/thread
__global__ void convert_x_kernel(const float* __restrict__ x,
                                 unsigned short* __restrict__ Xb, int n8) {
  int stride = gridDim.x * blockDim.x;
  for (int i = blockIdx.x * blockDim.x + threadIdx.x; i < n8; i += stride) {
    size_t base = (size_t)i * 8;
    float4v a = *(const float4v*)(x + base);
    float4v b = *(const float4v*)(x + base + 4);
    union { unsigned short s[8]; uint4 v; } o;
#pragma unroll
    for (int j = 0; j < 4; ++j) o.s[j] = f32_to_bf16_rne(a[j]);
#pragma unroll
    for (int j = 0; j < 4; ++j) o.s[4 + j] = f32_to_bf16_rne(b[j]);
    *(uint4*)(Xb + base) = o.v;
  }
}

// Stage one 128x64 bf16 half-tile into LDS (linear dest, inverse-swizzled global
// source chunk). 2 x global_load_lds(16B) per thread.
__device__ __forceinline__ void stageHalf(const unsigned short* __restrict__ G,
                                          int rowBase,
                                          unsigned short* halfBase,
                                          int tile, int srow, int sc, int wave) {
#pragma unroll
  for (int i = 0; i < 2; ++i) {
    const unsigned short* src =
        G + ((size_t)(rowBase + i * 64 + srow) << 12) + (tile << 6) + (sc << 3);
    unsigned short* dst = halfBase + i * 4096 + wave * 512;   // lane-uniform base
    __builtin_amdgcn_global_load_lds((const __attribute__((address_space(1))) unsigned int*)src,
                                     (__attribute__((address_space(3))) unsigned int*)dst, 16, 0, 0);
  }
}

// C[M][4096] = A[M][4096] * B[4096][4096]^T + bias; bf16 in, f32 out.
// 256x256 tile, BK=64, 8 waves (2Mx4N), 16x16x32 MFMA, 8 phases / 2 K-tiles,
// register-double-buffered fragments read ONE PHASE AHEAD so the LDS drain
// overlaps the MFMA cluster; 1 barrier/phase; counted vmcnt(2) at ph2/ph6.
__global__ __launch_bounds__(512, 2) void gemm_kernel(
    const unsigned short* __restrict__ A,   // [M][4096] bf16 bits
    const unsigned short* __restrict__ Bm,  // [4096][4096] bf16 bits (Wt)
    const float* __restrict__ bias,
    float* __restrict__ C,
    int M) {
  // [buf][op A=0/B=1][half][128*64 elements] = 128 KiB ; tile t -> buf t&1
  __shared__ unsigned short L[2][2][2][8192];

  const int t = threadIdx.x;
  const int lane = t & 63;
  const int wave = t >> 6;
  const int wm = wave >> 2;    // 0..1  (A-half = wm)
  const int wn = wave & 3;     // 0..3  (B-half = wn>>1)

  int id = blockIdx.x;
  int per = gridDim.x >> 3;               // bijective: grid % 8 == 0
  int swz = (id & 7) * per + (id >> 3);
  int bm = swz >> 4;                      // bm-stripe per XCD (R4-proven locality)
  int bn = swz & 15;
  const int brow = bm << 8;
  const int bcol = bn << 8;

  // 16x16 fragment addressing (R6, proven 0-conflict):
  // offset in [128][64] half = row*64 + (((ks*4 + ch) ^ (row&7)) << 3)
  const int r15 = lane & 15;
  const int ch = (lane >> 4) & 3;
  const int x7 = lane & 7;
  const int ko0 = ((ch ^ x7) << 3);
  const int ko1 = (((4 + ch) ^ x7) << 3);
  const int bRow = (wn & 1) * 64;
  const int srow = t >> 3;
  const int sc = (t & 7) ^ (srow & 7);

  const unsigned short* A0h = &L[0][0][wm][0];
  const unsigned short* B0h = &L[0][1][wn >> 1][0];
  const unsigned short* A1h = &L[1][0][wm][0];
  const unsigned short* B1h = &L[1][1][wn >> 1][0];

  f32x4 acc[8][4] = {};
  bf16x8 a[2][2][2];   // [set][rowpair][ks]
  bf16x8 b[2][4][2];   // [set][col][ks]

#define RD_A(S, Hp, rb) do {                                                  \
    a[S][0][0] = *(const bf16x8*)((Hp) + ((rb) * 32 + r15) * 64 + ko0);       \
    a[S][0][1] = *(const bf16x8*)((Hp) + ((rb) * 32 + r15) * 64 + ko1);       \
    a[S][1][0] = *(const bf16x8*)((Hp) + ((rb) * 32 + 16 + r15) * 64 + ko0);  \
    a[S][1][1] = *(const bf16x8*)((Hp) + ((rb) * 32 + 16 + r15) * 64 + ko1);  \
  } while (0)

#define RD_B(S, Hp) do {                                                      \
    _Pragma("unroll")                                                         \
    for (int j = 0; j < 4; ++j) {                                             \
      b[S][j][0] = *(const bf16x8*)((Hp) + (bRow + j * 16 + r15) * 64 + ko0); \
      b[S][j][1] = *(const bf16x8*)((Hp) + (bRow + j * 16 + r15) * 64 + ko1); \
    }                                                                         \
  } while (0)

#define MM(AS, BS, q) do {                                                    \
    __builtin_amdgcn_s_setprio(1);                                            \
    _Pragma("unroll")                                                         \
    for (int j = 0; j < 4; ++j) {                                             \
      acc[2*(q)][j]   = __builtin_amdgcn_mfma_f32_16x16x32_bf16(a[AS][0][0], b[BS][j][0], acc[2*(q)][j],   0, 0, 0); \
      acc[2*(q)][j]   = __builtin_amdgcn_mfma_f32_16x16x32_bf16(a[AS][0][1], b[BS][j][1], acc[2*(q)][j],   0, 0, 0); \
      acc[2*(q)+1][j] = __builtin_amdgcn_mfma_f32_16x16x32_bf16(a[AS][1][0], b[BS][j][0], acc[2*(q)+1][j], 0, 0, 0); \
      acc[2*(q)+1][j] = __builtin_amdgcn_mfma_f32_16x16x32_bf16(a[AS][1][1], b[BS][j][1], acc[2*(q)+1][j], 0, 0, 0); \
    }                                                                         \
    __builtin_amdgcn_s_setprio(0);                                            \
  } while (0)

  // DS may not sink below; MFMA may not hoist above; VALU/SALU/VMEM free.
#define SB  __builtin_amdgcn_sched_barrier(0x77)
#define BAR do { __builtin_amdgcn_s_barrier(); asm volatile("" ::: "memory"); } while (0)
#define VM(n) asm volatile("s_waitcnt vmcnt(" #n ")" ::: "memory")

  // prologue: stage B(0), A(0), B(1); wait B(0)+A(0); read frags for ph0
  stageHalf(Bm, bcol + 0,   &L[0][1][0][0], 0, srow, sc, wave);
  stageHalf(Bm, bcol + 128, &L[0][1][1][0], 0, srow, sc, wave);
  stageHalf(A,  brow + 0,   &L[0][0][0][0], 0, srow, sc, wave);
  stageHalf(A,  brow + 128, &L[0][0][1][0], 0, srow, sc, wave);
  stageHalf(Bm, bcol + 0,   &L[1][1][0][0], 1, srow, sc, wave);
  stageHalf(Bm, bcol + 128, &L[1][1][1][0], 1, srow, sc, wave);
  VM(4);
  BAR;
  RD_B(0, B0h);
  RD_A(0, A0h, 0);

  for (int it = 0; it < NITER - 1; ++it) {
    const int s = 2 * it;
    // ph0
    RD_A(1, A0h, 1); SB;
    stageHalf(A, brow + 0,    &L[1][0][0][0], s + 1, srow, sc, wave);
    MM(0, 0, 0); BAR;
    // ph1
    RD_A(0, A0h, 2); SB;
    stageHalf(A, brow + 128,  &L[1][0][1][0], s + 1, srow, sc, wave);
    MM(1, 0, 1); BAR;
    // ph2  (checkpoint: A(s+1),B(s+1) must land for ph3's reads)
    RD_A(1, A0h, 3); SB;
    stageHalf(Bm, bcol + 0,   &L[0][1][0][0], s + 2, srow, sc, wave);
    MM(0, 0, 2); VM(2); BAR;
    // ph3
    RD_B(1, B1h); RD_A(0, A1h, 0); SB;
    stageHalf(Bm, bcol + 128, &L[0][1][1][0], s + 2, srow, sc, wave);
    MM(1, 0, 3); BAR;
    // ph4
    RD_A(1, A1h, 1); SB;
    stageHalf(A, brow + 0,    &L[0][0][0][0], s + 2, srow, sc, wave);
    MM(0, 1, 0); BAR;
    // ph5
    RD_A(0, A1h, 2); SB;
    stageHalf(A, brow + 128,  &L[0][0][1][0], s + 2, srow, sc, wave);
    MM(1, 1, 1); BAR;
    // ph6  (checkpoint: A(s+2),B(s+2) must land for ph7's reads)
    RD_A(1, A1h, 3); SB;
    stageHalf(Bm, bcol + 0,   &L[1][1][0][0], s + 3, srow, sc, wave);
    MM(0, 1, 2); VM(2); BAR;
    // ph7
    RD_B(0, B0h); RD_A(0, A0h, 0); SB;
    stageHalf(Bm, bcol + 128, &L[1][1][1][0], s + 3, srow, sc, wave);
    MM(1, 1, 3); BAR;
  }

  // peeled last iteration (tiles NT-2, NT-1): only A(NT-1) left to stage
  RD_A(1, A0h, 1); SB;
  stageHalf(A, brow + 0,   &L[1][0][0][0], NT - 1, srow, sc, wave);
  MM(0, 0, 0); BAR;
  RD_A(0, A0h, 2); SB;
  stageHalf(A, brow + 128, &L[1][0][1][0], NT - 1, srow, sc, wave);
  MM(1, 0, 1); BAR;
  RD_A(1, A0h, 3); SB;
  MM(0, 0, 2); VM(0); BAR;          // drain: A(63),B(63) all landed
  RD_B(1, B1h); RD_A(0, A1h, 0); SB;
  MM(1, 0, 3); BAR;
  RD_A(1, A1h, 1); SB;
  MM(0, 1, 0); BAR;
  RD_A(0, A1h, 2); SB;
  MM(1, 1, 1); BAR;
  RD_A(1, A1h, 3); SB;
  MM(0, 1, 2); BAR;
  MM(1, 1, 3);

#undef RD_A
#undef RD_B
#undef MM
#undef SB
#undef BAR
#undef VM

  // epilogue: 16x16 C/D layout col=lane&15, row=(lane>>4)*4+reg
  const int cr = (lane >> 4) << 2;
#pragma unroll
  for (int fr = 0; fr < 8; ++fr) {
    int row = brow + (wm << 7) + fr * 16 + cr;
#pragma unroll
    for (int fc = 0; fc < 4; ++fc) {
      int col = bcol + (wn << 6) + fc * 16 + r15;
      float bv = bias[col];
      float* cp = C + ((size_t)row << 12) + col;
#pragma unroll
      for (int r = 0; r < 4; ++r)
        cp[(size_t)r << 12] = acc[fr][fc][r] + bv;
    }
  }
}

extern "C" void kernel_launch(void* const* d_in, const int* in_sizes, int n_in,
                              void* d_out, int out_size, void* d_ws, size_t ws_size,
                              hipStream_t stream) {
  const float* x     = (const float*)d_in[0];
  const float* psi   = (const float*)d_in[1];
  const float* omega = (const float*)d_in[2];
  const float* g     = (const float*)d_in[3];
  const float* bias  = (const float*)d_in[4];

  const int M = in_sizes[0] / DFEAT;   // 8192
  const int N = DFEAT;
  const int K = DFEAT;

  unsigned short* Wt = (unsigned short*)d_ws;                              // 32 MB
  unsigned short* Xb = (unsigned short*)((char*)d_ws + (size_t)N * K * 2); // 64 MB

  build_wt_kernel<<<DFEAT, 256, 0, stream>>>(psi, omega, g, Wt);

  int n8 = (M * K) / 8;
  convert_x_kernel<<<2048, 256, 0, stream>>>(x, Xb, n8);

  int nwg = (M / 256) * (N / 256);   // 32*16 = 512, divisible by 8
  gemm_kernel<<<nwg, 512, 0, stream>>>(Xb, Wt, bias, (float*)d_out, M);
}

// Round 9
// 309.673 us; speedup vs baseline: 1.2903x; 1.2903x over previous
//
#include <hip/hip_runtime.h>
#include <hip/hip_bf16.h>

#define DFEAT 4096
#define NT 64        // K-tiles of 64
#define NITER 32     // 2 K-tiles per iteration

typedef __attribute__((ext_vector_type(8))) short bf16x8;
typedef __attribute__((ext_vector_type(4))) float f32x4;
typedef __attribute__((ext_vector_type(4))) float float4v;

__device__ inline unsigned short f32_to_bf16_rne(float f) {
  union { float f; unsigned u; } v; v.f = f;
  unsigned u = v.u;
  unsigned r = u + 0x7fffu + ((u >> 16) & 1u);
  return (unsigned short)(r >> 16);
}

// Wt[n][k] = psi[k] * sum_r omega[r][n] * g[r][(n-k)&4095], bf16, row-major.
// 2 rows per block (blockIdx.x*2 + threadIdx.y), 4 bf16 per thread store (uint2).
__global__ void build_wt_kernel(const float* __restrict__ psi,
                                const float* __restrict__ omega,
                                const float* __restrict__ g,
                                unsigned short* __restrict__ Wt) {
  int n = blockIdx.x * 2 + threadIdx.y;
  float o0 = omega[n];
  float o1 = omega[DFEAT + n];
  float o2 = omega[2 * DFEAT + n];
  const float* g0 = g;
  const float* g1 = g + DFEAT;
  const float* g2 = g + 2 * DFEAT;
  for (int k0 = threadIdx.x * 4; k0 < DFEAT; k0 += blockDim.x * 4) {
    unsigned short res[4];
#pragma unroll
    for (int j = 0; j < 4; ++j) {
      int k = k0 + j;
      int idx = (n - k) & (DFEAT - 1);
      float w = o0 * g0[idx] + o1 * g1[idx] + o2 * g2[idx];
      w *= psi[k];
      res[j] = f32_to_bf16_rne(w);
    }
    uint2 pk;
    pk.x = (unsigned)res[0] | ((unsigned)res[1] << 16);
    pk.y = (unsigned)res[2] | ((unsigned)res[3] << 16);
    *(uint2*)(Wt + (size_t)n * DFEAT + k0) = pk;
  }
}

// x (f32) -> bf16 bits, 8 elements/thread
__global__ void convert_x_kernel(const float* __restrict__ x,
                                 unsigned short* __restrict__ Xb, int n8) {
  int stride = gridDim.x * blockDim.x;
  for (int i = blockIdx.x * blockDim.x + threadIdx.x; i < n8; i += stride) {
    size_t base = (size_t)i * 8;
    float4v a = *(const float4v*)(x + base);
    float4v b = *(const float4v*)(x + base + 4);
    union { unsigned short s[8]; uint4 v; } o;
#pragma unroll
    for (int j = 0; j < 4; ++j) o.s[j] = f32_to_bf16_rne(a[j]);
#pragma unroll
    for (int j = 0; j < 4; ++j) o.s[4 + j] = f32_to_bf16_rne(b[j]);
    *(uint4*)(Xb + base) = o.v;
  }
}

// Stage one 128x64 bf16 half-tile into LDS (linear dest, inverse-swizzled global
// source chunk). 2 x global_load_lds(16B) per thread.
__device__ __forceinline__ void stageHalf(const unsigned short* __restrict__ G,
                                          int rowBase,
                                          unsigned short* halfBase,
                                          int tile, int srow, int sc, int wave) {
#pragma unroll
  for (int i = 0; i < 2; ++i) {
    const unsigned short* src =
        G + ((size_t)(rowBase + i * 64 + srow) << 12) + (tile << 6) + (sc << 3);
    unsigned short* dst = halfBase + i * 4096 + wave * 512;   // lane-uniform base
    __builtin_amdgcn_global_load_lds((const __attribute__((address_space(1))) unsigned int*)src,
                                     (__attribute__((address_space(3))) unsigned int*)dst, 16, 0, 0);
  }
}

// C[M][4096] = A[M][4096] * B[4096][4096]^T + bias; bf16 in, f32 out.
// 8-phase schedule (R6-proven): 256x256 tile, BK=64, 8 waves (2Mx4N),
// 2 K-tiles/iter, 16x16x32 MFMA, vmcnt(4) checkpoints at ph3/ph7.
__global__ __launch_bounds__(512, 2) void gemm_kernel(
    const unsigned short* __restrict__ A,   // [M][4096] bf16 bits
    const unsigned short* __restrict__ Bm,  // [4096][4096] bf16 bits (Wt)
    const float* __restrict__ bias,
    float* __restrict__ C,
    int M) {
  // [buf][op A=0/B=1][half][128*64 elements] = 128 KiB
  __shared__ unsigned short L[2][2][2][8192];

  const int t = threadIdx.x;
  const int lane = t & 63;
  const int wave = t >> 6;
  const int wm = wave >> 2;    // 0..1  (A-half = wm)
  const int wn = wave & 3;     // 0..3  (B-half = wn>>1)

  int id = blockIdx.x;
  int per = gridDim.x >> 3;               // bijective: grid % 8 == 0
  int swz = (id & 7) * per + (id >> 3);
  int bm = swz >> 4;                      // bm-stripe per XCD (R4-proven locality)
  int bn = swz & 15;
  const int brow = bm << 8;
  const int bcol = bn << 8;

  // fragment addressing: element offset within a [128][64] half =
  //   row*64 + ((ks*4 + chunk) ^ (row&7)) * 8 ; row&7 == lane&7 for all frags
  const int r15 = lane & 15;
  const int ch = (lane >> 4) & 3;
  const int x7 = lane & 7;
  const int ko0 = ((ch ^ x7) << 3);         // ks=0
  const int ko1 = (((4 + ch) ^ x7) << 3);   // ks=1
  const int bRow = (wn & 1) * 64;
  // staging per-thread constants
  const int srow = t >> 3;                  // 0..63 per call-half
  const int sc = (t & 7) ^ (srow & 7);      // inverse-swizzled source chunk

  const unsigned short* A0h = &L[0][0][wm][0];
  const unsigned short* B0h = &L[0][1][wn >> 1][0];
  const unsigned short* A1h = &L[1][0][wm][0];
  const unsigned short* B1h = &L[1][1][wn >> 1][0];

  f32x4 acc[8][4] = {};
  bf16x8 a[2][2], b[4][2];

#define RD_A(Hp, q) do {                                                      \
    a[0][0] = *(const bf16x8*)((Hp) + ((q) * 32 + 0 + r15) * 64 + ko0);       \
    a[0][1] = *(const bf16x8*)((Hp) + ((q) * 32 + 0 + r15) * 64 + ko1);       \
    a[1][0] = *(const bf16x8*)((Hp) + ((q) * 32 + 16 + r15) * 64 + ko0);      \
    a[1][1] = *(const bf16x8*)((Hp) + ((q) * 32 + 16 + r15) * 64 + ko1);      \
  } while (0)

#define RD_B(Hp) do {                                                         \
    _Pragma("unroll")                                                         \
    for (int j = 0; j < 4; ++j) {                                             \
      b[j][0] = *(const bf16x8*)((Hp) + (bRow + j * 16 + r15) * 64 + ko0);    \
      b[j][1] = *(const bf16x8*)((Hp) + (bRow + j * 16 + r15) * 64 + ko1);    \
    }                                                                         \
  } while (0)

#define MM(q) do {                                                            \
    __builtin_amdgcn_s_setprio(1);                                            \
    _Pragma("unroll")                                                         \
    for (int j = 0; j < 4; ++j) {                                             \
      acc[2*(q)][j]   = __builtin_amdgcn_mfma_f32_16x16x32_bf16(a[0][0], b[j][0], acc[2*(q)][j],   0, 0, 0); \
      acc[2*(q)][j]   = __builtin_amdgcn_mfma_f32_16x16x32_bf16(a[0][1], b[j][1], acc[2*(q)][j],   0, 0, 0); \
      acc[2*(q)+1][j] = __builtin_amdgcn_mfma_f32_16x16x32_bf16(a[1][0], b[j][0], acc[2*(q)+1][j], 0, 0, 0); \
      acc[2*(q)+1][j] = __builtin_amdgcn_mfma_f32_16x16x32_bf16(a[1][1], b[j][1], acc[2*(q)+1][j], 0, 0, 0); \
    }                                                                         \
    __builtin_amdgcn_s_setprio(0);                                            \
  } while (0)

#define BAR do { __builtin_amdgcn_s_barrier(); asm volatile("" ::: "memory"); } while (0)

  // prologue: B(0), A(0), B(1) staged (12 gloads); wait all but B(1)
  stageHalf(Bm, bcol + 0,   &L[0][1][0][0], 0, srow, sc, wave);
  stageHalf(Bm, bcol + 128, &L[0][1][1][0], 0, srow, sc, wave);
  stageHalf(A,  brow + 0,   &L[0][0][0][0], 0, srow, sc, wave);
  stageHalf(A,  brow + 128, &L[0][0][1][0], 0, srow, sc, wave);
  stageHalf(Bm, bcol + 0,   &L[1][1][0][0], 1, srow, sc, wave);
  stageHalf(Bm, bcol + 128, &L[1][1][1][0], 1, srow, sc, wave);
  asm volatile("s_waitcnt vmcnt(4)" ::: "memory");
  BAR;

  for (int it = 0; it < NITER - 1; ++it) {
    const int s = 2 * it;
    // ph0: tile s quadrant 0 (+ all B(s) frags); stage Ah0(s+1)
    RD_B(B0h); RD_A(A0h, 0);
    stageHalf(A, brow + 0,    &L[1][0][0][0], s + 1, srow, sc, wave);
    BAR; MM(0); BAR;
    // ph1
    RD_A(A0h, 1);
    stageHalf(A, brow + 128,  &L[1][0][1][0], s + 1, srow, sc, wave);
    BAR; MM(1); BAR;
    // ph2
    RD_A(A0h, 2);
    stageHalf(Bm, bcol + 0,   &L[0][1][0][0], s + 2, srow, sc, wave);
    BAR; MM(2); BAR;
    // ph3: checkpoint — A(s+1), B(s+1) landed; leave B(s+2) in flight
    RD_A(A0h, 3);
    stageHalf(Bm, bcol + 128, &L[0][1][1][0], s + 2, srow, sc, wave);
    BAR; MM(3);
    asm volatile("s_waitcnt vmcnt(4)" ::: "memory");
    BAR;
    // ph4: tile s+1 quadrant 0
    RD_B(B1h); RD_A(A1h, 0);
    stageHalf(A, brow + 0,    &L[0][0][0][0], s + 2, srow, sc, wave);
    BAR; MM(0); BAR;
    // ph5
    RD_A(A1h, 1);
    stageHalf(A, brow + 128,  &L[0][0][1][0], s + 2, srow, sc, wave);
    BAR; MM(1); BAR;
    // ph6
    RD_A(A1h, 2);
    stageHalf(Bm, bcol + 0,   &L[1][1][0][0], s + 3, srow, sc, wave);
    BAR; MM(2); BAR;
    // ph7: checkpoint — A(s+2), B(s+2) landed; leave B(s+3) in flight
    RD_A(A1h, 3);
    stageHalf(Bm, bcol + 128, &L[1][1][1][0], s + 3, srow, sc, wave);
    BAR; MM(3);
    asm volatile("s_waitcnt vmcnt(4)" ::: "memory");
    BAR;
  }

  // peeled last iteration (tiles NT-2, NT-1): only A(NT-1) still to stage
  RD_B(B0h); RD_A(A0h, 0);
  stageHalf(A, brow + 0,   &L[1][0][0][0], NT - 1, srow, sc, wave);
  BAR; MM(0); BAR;
  RD_A(A0h, 1);
  stageHalf(A, brow + 128, &L[1][0][1][0], NT - 1, srow, sc, wave);
  BAR; MM(1); BAR;
  RD_A(A0h, 2); BAR; MM(2); BAR;
  RD_A(A0h, 3); BAR; MM(3);
  asm volatile("s_waitcnt vmcnt(0)" ::: "memory");
  BAR;
  RD_B(B1h); RD_A(A1h, 0); BAR; MM(0); BAR;
  RD_A(A1h, 1); BAR; MM(1); BAR;
  RD_A(A1h, 2); BAR; MM(2); BAR;
  RD_A(A1h, 3); BAR; MM(3);

#undef RD_A
#undef RD_B
#undef MM
#undef BAR

  // epilogue: 16x16 C/D layout col=lane&15, row=(lane>>4)*4+reg
  const int cr = (lane >> 4) << 2;
#pragma unroll
  for (int fr = 0; fr < 8; ++fr) {
    int row = brow + (wm << 7) + fr * 16 + cr;
#pragma unroll
    for (int fc = 0; fc < 4; ++fc) {
      int col = bcol + (wn << 6) + fc * 16 + r15;
      float bv = bias[col];
      float* cp = C + ((size_t)row << 12) + col;
#pragma unroll
      for (int r = 0; r < 4; ++r)
        cp[(size_t)r << 12] = acc[fr][fc][r] + bv;
    }
  }
}

extern "C" void kernel_launch(void* const* d_in, const int* in_sizes, int n_in,
                              void* d_out, int out_size, void* d_ws, size_t ws_size,
                              hipStream_t stream) {
  const float* x     = (const float*)d_in[0];
  const float* psi   = (const float*)d_in[1];
  const float* omega = (const float*)d_in[2];
  const float* g     = (const float*)d_in[3];
  const float* bias  = (const float*)d_in[4];

  const int M = in_sizes[0] / DFEAT;   // 8192
  const int N = DFEAT;
  const int K = DFEAT;

  unsigned short* Wt = (unsigned short*)d_ws;                              // 32 MB
  unsigned short* Xb = (unsigned short*)((char*)d_ws + (size_t)N * K * 2); // 64 MB

  dim3 wtb(128, 2);
  build_wt_kernel<<<DFEAT / 2, wtb, 0, stream>>>(psi, omega, g, Wt);

  int n8 = (M * K) / 8;
  convert_x_kernel<<<2048, 256, 0, stream>>>(x, Xb, n8);

  int nwg = (M / 256) * (N / 256);   // 32*16 = 512, divisible by 8
  gemm_kernel<<<nwg, 512, 0, stream>>>(Xb, Wt, bias, (float*)d_out, M);
}

// Round 10
// 276.440 us; speedup vs baseline: 1.4454x; 1.1202x over previous
//
#include <hip/hip_runtime.h>
#include <hip/hip_bf16.h>

#define DFEAT 4096
#define NT 64        // K-tiles of 64
#define NITER 32     // 2 K-tiles per iteration

typedef __attribute__((ext_vector_type(8))) short bf16x8;
typedef __attribute__((ext_vector_type(4))) float f32x4;
typedef __attribute__((ext_vector_type(4))) float float4v;

__device__ inline unsigned short f32_to_bf16_rne(float f) {
  union { float f; unsigned u; } v; v.f = f;
  unsigned u = v.u;
  unsigned r = u + 0x7fffu + ((u >> 16) & 1u);
  return (unsigned short)(r >> 16);
}

// Wt[n][k] = psi[k] * sum_r omega[r][n] * g[r][(n-k)&4095], bf16, row-major [4096][4096]
// (R6 form — measured at the prep floor; R9's uint2 variant regressed, reverted)
__global__ void build_wt_kernel(const float* __restrict__ psi,
                                const float* __restrict__ omega,
                                const float* __restrict__ g,
                                unsigned short* __restrict__ Wt) {
  int n = blockIdx.x;
  float o0 = omega[n];
  float o1 = omega[DFEAT + n];
  float o2 = omega[2 * DFEAT + n];
  const float* g0 = g;
  const float* g1 = g + DFEAT;
  const float* g2 = g + 2 * DFEAT;
  for (int k = threadIdx.x; k < DFEAT; k += blockDim.x) {
    int idx = (n - k) & (DFEAT - 1);
    float w = o0 * g0[idx] + o1 * g1[idx] + o2 * g2[idx];
    w *= psi[k];
    Wt[(size_t)n * DFEAT + k] = f32_to_bf16_rne(w);
  }
}

// x (f32) -> bf16 bits, 8 elements/thread
__global__ void convert_x_kernel(const float* __restrict__ x,
                                 unsigned short* __restrict__ Xb, int n8) {
  int stride = gridDim.x * blockDim.x;
  for (int i = blockIdx.x * blockDim.x + threadIdx.x; i < n8; i += stride) {
    size_t base = (size_t)i * 8;
    float4v a = *(const float4v*)(x + base);
    float4v b = *(const float4v*)(x + base + 4);
    union { unsigned short s[8]; uint4 v; } o;
#pragma unroll
    for (int j = 0; j < 4; ++j) o.s[j] = f32_to_bf16_rne(a[j]);
#pragma unroll
    for (int j = 0; j < 4; ++j) o.s[4 + j] = f32_to_bf16_rne(b[j]);
    *(uint4*)(Xb + base) = o.v;
  }
}

// Stage one 128x64 bf16 half-tile into LDS (linear dest, inverse-swizzled global
// source chunk). 2 x global_load_lds(16B) per thread.
__device__ __forceinline__ void stageHalf(const unsigned short* __restrict__ G,
                                          int rowBase,
                                          unsigned short* halfBase,
                                          int tile, int srow, int sc, int wave) {
#pragma unroll
  for (int i = 0; i < 2; ++i) {
    const unsigned short* src =
        G + ((size_t)(rowBase + i * 64 + srow) << 12) + (tile << 6) + (sc << 3);
    unsigned short* dst = halfBase + i * 4096 + wave * 512;   // lane-uniform base
    __builtin_amdgcn_global_load_lds((const __attribute__((address_space(1))) unsigned int*)src,
                                     (__attribute__((address_space(3))) unsigned int*)dst, 16, 0, 0);
  }
}

// C[M][4096] = A[M][4096] * B[4096][4096]^T + bias; bf16 in, f32 out.
// 8-phase schedule, ONE barrier per phase (RD; stage; MM; BAR): in-wave counted
// lgkmcnt lets MFMA start while reads drain; cross-wave RD/MM overlap on a SIMD.
// Slot ledger re-verified for 1-barrier phases; vmcnt(4) checkpoints at ph3/ph7.
__global__ __launch_bounds__(512, 2) void gemm_kernel(
    const unsigned short* __restrict__ A,   // [M][4096] bf16 bits
    const unsigned short* __restrict__ Bm,  // [4096][4096] bf16 bits (Wt)
    const float* __restrict__ bias,
    float* __restrict__ C,
    int M) {
  // [buf][op A=0/B=1][half][128*64 elements] = 128 KiB
  __shared__ unsigned short L[2][2][2][8192];

  const int t = threadIdx.x;
  const int lane = t & 63;
  const int wave = t >> 6;
  const int wm = wave >> 2;    // 0..1  (A-half = wm)
  const int wn = wave & 3;     // 0..3  (B-half = wn>>1)

  int id = blockIdx.x;
  int per = gridDim.x >> 3;               // bijective: grid % 8 == 0
  int swz = (id & 7) * per + (id >> 3);
  int bm = swz >> 4;                      // bm-stripe per XCD (R4-proven locality)
  int bn = swz & 15;
  const int brow = bm << 8;
  const int bcol = bn << 8;

  // fragment addressing: element offset within a [128][64] half =
  //   row*64 + ((ks*4 + chunk) ^ (row&7)) * 8 ; row&7 == lane&7 for all frags
  const int r15 = lane & 15;
  const int ch = (lane >> 4) & 3;
  const int x7 = lane & 7;
  const int ko0 = ((ch ^ x7) << 3);         // ks=0
  const int ko1 = (((4 + ch) ^ x7) << 3);   // ks=1
  const int bRow = (wn & 1) * 64;
  // staging per-thread constants
  const int srow = t >> 3;                  // 0..63 per call-half
  const int sc = (t & 7) ^ (srow & 7);      // inverse-swizzled source chunk

  const unsigned short* A0h = &L[0][0][wm][0];
  const unsigned short* B0h = &L[0][1][wn >> 1][0];
  const unsigned short* A1h = &L[1][0][wm][0];
  const unsigned short* B1h = &L[1][1][wn >> 1][0];

  f32x4 acc[8][4] = {};
  bf16x8 a[2][2], b[4][2];

#define RD_A(Hp, q) do {                                                      \
    a[0][0] = *(const bf16x8*)((Hp) + ((q) * 32 + 0 + r15) * 64 + ko0);       \
    a[0][1] = *(const bf16x8*)((Hp) + ((q) * 32 + 0 + r15) * 64 + ko1);       \
    a[1][0] = *(const bf16x8*)((Hp) + ((q) * 32 + 16 + r15) * 64 + ko0);      \
    a[1][1] = *(const bf16x8*)((Hp) + ((q) * 32 + 16 + r15) * 64 + ko1);      \
  } while (0)

#define RD_B(Hp) do {                                                         \
    _Pragma("unroll")                                                         \
    for (int j = 0; j < 4; ++j) {                                             \
      b[j][0] = *(const bf16x8*)((Hp) + (bRow + j * 16 + r15) * 64 + ko0);    \
      b[j][1] = *(const bf16x8*)((Hp) + (bRow + j * 16 + r15) * 64 + ko1);    \
    }                                                                         \
  } while (0)

#define MM(q) do {                                                            \
    __builtin_amdgcn_s_setprio(1);                                            \
    _Pragma("unroll")                                                         \
    for (int j = 0; j < 4; ++j) {                                             \
      acc[2*(q)][j]   = __builtin_amdgcn_mfma_f32_16x16x32_bf16(a[0][0], b[j][0], acc[2*(q)][j],   0, 0, 0); \
      acc[2*(q)][j]   = __builtin_amdgcn_mfma_f32_16x16x32_bf16(a[0][1], b[j][1], acc[2*(q)][j],   0, 0, 0); \
      acc[2*(q)+1][j] = __builtin_amdgcn_mfma_f32_16x16x32_bf16(a[1][0], b[j][0], acc[2*(q)+1][j], 0, 0, 0); \
      acc[2*(q)+1][j] = __builtin_amdgcn_mfma_f32_16x16x32_bf16(a[1][1], b[j][1], acc[2*(q)+1][j], 0, 0, 0); \
    }                                                                         \
    __builtin_amdgcn_s_setprio(0);                                            \
  } while (0)

#define BAR do { __builtin_amdgcn_s_barrier(); asm volatile("" ::: "memory"); } while (0)

  // prologue: B(0), A(0), B(1) staged (12 gloads); wait all but B(1)
  stageHalf(Bm, bcol + 0,   &L[0][1][0][0], 0, srow, sc, wave);
  stageHalf(Bm, bcol + 128, &L[0][1][1][0], 0, srow, sc, wave);
  stageHalf(A,  brow + 0,   &L[0][0][0][0], 0, srow, sc, wave);
  stageHalf(A,  brow + 128, &L[0][0][1][0], 0, srow, sc, wave);
  stageHalf(Bm, bcol + 0,   &L[1][1][0][0], 1, srow, sc, wave);
  stageHalf(Bm, bcol + 128, &L[1][1][1][0], 1, srow, sc, wave);
  asm volatile("s_waitcnt vmcnt(4)" ::: "memory");
  BAR;

  for (int it = 0; it < NITER - 1; ++it) {
    const int s = 2 * it;
    // ph0: tile s quadrant 0 (+ all B(s) frags); stage Ah0(s+1)
    RD_B(B0h); RD_A(A0h, 0);
    stageHalf(A, brow + 0,    &L[1][0][0][0], s + 1, srow, sc, wave);
    MM(0); BAR;
    // ph1
    RD_A(A0h, 1);
    stageHalf(A, brow + 128,  &L[1][0][1][0], s + 1, srow, sc, wave);
    MM(1); BAR;
    // ph2
    RD_A(A0h, 2);
    stageHalf(Bm, bcol + 0,   &L[0][1][0][0], s + 2, srow, sc, wave);
    MM(2); BAR;
    // ph3: checkpoint — A(s+1), B(s+1) landed; leave B(s+2) in flight
    RD_A(A0h, 3);
    stageHalf(Bm, bcol + 128, &L[0][1][1][0], s + 2, srow, sc, wave);
    MM(3);
    asm volatile("s_waitcnt vmcnt(4)" ::: "memory");
    BAR;
    // ph4: tile s+1 quadrant 0
    RD_B(B1h); RD_A(A1h, 0);
    stageHalf(A, brow + 0,    &L[0][0][0][0], s + 2, srow, sc, wave);
    MM(0); BAR;
    // ph5
    RD_A(A1h, 1);
    stageHalf(A, brow + 128,  &L[0][0][1][0], s + 2, srow, sc, wave);
    MM(1); BAR;
    // ph6
    RD_A(A1h, 2);
    stageHalf(Bm, bcol + 0,   &L[1][1][0][0], s + 3, srow, sc, wave);
    MM(2); BAR;
    // ph7: checkpoint — A(s+2), B(s+2) landed; leave B(s+3) in flight
    RD_A(A1h, 3);
    stageHalf(Bm, bcol + 128, &L[1][1][1][0], s + 3, srow, sc, wave);
    MM(3);
    asm volatile("s_waitcnt vmcnt(4)" ::: "memory");
    BAR;
  }

  // peeled last iteration (tiles NT-2, NT-1): only A(NT-1) still to stage
  RD_B(B0h); RD_A(A0h, 0);
  stageHalf(A, brow + 0,   &L[1][0][0][0], NT - 1, srow, sc, wave);
  MM(0); BAR;
  RD_A(A0h, 1);
  stageHalf(A, brow + 128, &L[1][0][1][0], NT - 1, srow, sc, wave);
  MM(1); BAR;
  RD_A(A0h, 2); MM(2); BAR;
  RD_A(A0h, 3); MM(3);
  asm volatile("s_waitcnt vmcnt(0)" ::: "memory");
  BAR;
  RD_B(B1h); RD_A(A1h, 0); MM(0); BAR;
  RD_A(A1h, 1); MM(1); BAR;
  RD_A(A1h, 2); MM(2); BAR;
  RD_A(A1h, 3); MM(3);

#undef RD_A
#undef RD_B
#undef MM
#undef BAR

  // epilogue: 16x16 C/D layout col=lane&15, row=(lane>>4)*4+reg
  const int cr = (lane >> 4) << 2;
#pragma unroll
  for (int fr = 0; fr < 8; ++fr) {
    int row = brow + (wm << 7) + fr * 16 + cr;
#pragma unroll
    for (int fc = 0; fc < 4; ++fc) {
      int col = bcol + (wn << 6) + fc * 16 + r15;
      float bv = bias[col];
      float* cp = C + ((size_t)row << 12) + col;
#pragma unroll
      for (int r = 0; r < 4; ++r)
        cp[(size_t)r << 12] = acc[fr][fc][r] + bv;
    }
  }
}

extern "C" void kernel_launch(void* const* d_in, const int* in_sizes, int n_in,
                              void* d_out, int out_size, void* d_ws, size_t ws_size,
                              hipStream_t stream) {
  const float* x     = (const float*)d_in[0];
  const float* psi   = (const float*)d_in[1];
  const float* omega = (const float*)d_in[2];
  const float* g     = (const float*)d_in[3];
  const float* bias  = (const float*)d_in[4];

  const int M = in_sizes[0] / DFEAT;   // 8192
  const int N = DFEAT;
  const int K = DFEAT;

  unsigned short* Wt = (unsigned short*)d_ws;                              // 32 MB
  unsigned short* Xb = (unsigned short*)((char*)d_ws + (size_t)N * K * 2); // 64 MB

  build_wt_kernel<<<DFEAT, 256, 0, stream>>>(psi, omega, g, Wt);

  int n8 = (M * K) / 8;
  convert_x_kernel<<<2048, 256, 0, stream>>>(x, Xb, n8);

  int nwg = (M / 256) * (N / 256);   // 32*16 = 512, divisible by 8
  gemm_kernel<<<nwg, 512, 0, stream>>>(Xb, Wt, bias, (float*)d_out, M);
}